// Round 12
// baseline (162.796 us; speedup 1.0000x reference)
//
#include <hip/hip_runtime.h>
#include <math.h>

// Single-column ocean model: 2048 cols x 128 levels, 400 steps, 10 snapshots.
// v11 = v9's layout with the whole-wave DPP shifts REMOVED from the loop.
// Evidence: v9 (13 deps, 2 waves/SIMD) == v10 (8 deps, 4 waves/SIMD) == ~477
// cy/step/SIMD -> neither issue nor fma-chain binds; the shared factor is the
// 2 wave_shr1/wave_shl1 (legacy wf_* DPP) in the dependent chain, suspected
// ~200cy each. v11 delivers the SAME carry values using fast row-DPP +
// row_bcast15 (fwd) and row-DPP + one broadcast ds_swizzle (bwd), blended by
// precomputed 0/1 lane weights (full-exec fma blend -- NO divergence, which
// was v2's actual bug).
//   fwd : X  = m16 * bcast15(P3) + row_shr1(P3)   (m16=1 only @ segLane16)
//   bwd : Xb = m15 * swz16(S0)   + row_shl1(S0)   (m15=1 only @ segLane15)
// Layout: wave = 2 columns (32-lane segments), 4 levels/lane, both coupled
// fields in-lane (t+s | u+v) -> 2048 waves = 2/SIMD. Carries truncated to
// nearest neighbor (PROVEN: v9 passed absmax 0.25, identical truncation).
// Segment boundaries: a[0]=0 -> Ap=0 @ segLane0; cp[127]=0 -> Absuf=0 @ 31.
// Inner loop unroll 2. Coriolis lane-local.

namespace {
constexpr int NZv   = 128;
constexpr int Bv    = 2048;
constexpr int NOUTv = 40;
constexpr int NSNAP = 10;
constexpr float DTf      = 50.0f;
constexpr float FCORf    = 1.0e-4f;
constexpr float TFLX_SFC = -5.0e-5f;
constexpr float SFLX_SFC = 1.0e-6f;
constexpr float RFLX_SFC = 3.7e-5f;
constexpr float USTR_SFC = 1.0e-4f;
constexpr float CPf      = 3985.0f;

template <int CTRL>
__device__ __forceinline__ float dpp_zero(float x) {
  // DPP move, invalid source lane -> 0 (bound_ctrl = true)
  return __int_as_float(__builtin_amdgcn_update_dpp(
      0, __float_as_int(x), CTRL, 0xF, 0xF, true));
}
__device__ __forceinline__ float swz16(float x) {
  // BitMode and=0 or=16 xor=0: lanes 0-31 read lane 16, lanes 32-63 read 48.
  // Same-source broadcast -> bank-conflict-free.
  return __int_as_float(__builtin_amdgcn_ds_swizzle(__float_as_int(x), 0x0200));
}
constexpr int ROW_SHR1 = 0x111, ROW_SHL1 = 0x101, ROW_BCAST15 = 0x142;
} // namespace

__global__ void __launch_bounds__(256)
__attribute__((amdgpu_waves_per_eu(2, 2)))
scm_kernel(
    const float* __restrict__ u_in, const float* __restrict__ v_in,
    const float* __restrict__ t_in, const float* __restrict__ s_in,
    const float* __restrict__ akv,  const float* __restrict__ akt,
    const float* __restrict__ eps,  const float* __restrict__ hz,
    float* __restrict__ out) {
  __shared__ float zw[NZv + 1];
  __shared__ float sh_abc[4][2][3][NZv]; // [wave][colInWave][a,b,c][k]
  __shared__ float sh_cpp[4][2][2][NZv]; // [wave][colInWave][cp,p][k]

  const int tid     = threadIdx.x;
  const int lane    = tid & 63;
  const int wid     = tid >> 6;           // 0..3
  const bool isM    = (wid & 1) != 0;     // momentum wave (u+v) vs tracer (t+s)
  const int cw      = lane >> 5;          // column within wave: 0 or 1
  const int segLane = lane & 31;          // position within 32-lane segment
  const int col     = blockIdx.x * 4 + (wid >> 1) * 2 + cw;
  const int k0      = segLane * 4;

  // ---- zw (w-point depths, cumsum of hz) -------------------------------
  if (tid == 0) {
    float tot = 0.f;
    for (int k = 0; k < NZv; ++k) tot += hz[k];
    float run = 0.f;
    zw[0] = -tot;
    for (int k = 0; k < NZv; ++k) { run += hz[k]; zw[k + 1] = run - tot; }
  }
  __syncthreads();

  // ---- tridiag coefficients (fixed in time; shared by the field pair) ---
  const float* Kp = isM ? akv : akt;
  float a_[4], c_[4], b_[4], hzv[4];
#pragma unroll
  for (int j = 0; j < 4; ++j) {
    const int k = k0 + j;
    const float hzk = hz[k];
    hzv[j] = hzk;
    const float Kk  = Kp[col * (NZv + 1) + k];
    const float Kk1 = Kp[col * (NZv + 1) + k + 1];
    float aj = 0.f, cj = 0.f;
    if (k > 0)       { const float dzm = 0.5f * (hz[k - 1] + hzk); aj = -DTf * Kk  / (hzk * dzm); }
    if (k < NZv - 1) { const float dzp = 0.5f * (hzk + hz[k + 1]); cj = -DTf * Kk1 / (hzk * dzp); }
    a_[j] = aj; c_[j] = cj; b_[j] = 1.f - aj - cj;
  }
#pragma unroll
  for (int j = 0; j < 4; ++j) {
    sh_abc[wid][cw][0][k0 + j] = a_[j];
    sh_abc[wid][cw][1][k0 + j] = b_[j];
    sh_abc[wid][cw][2][k0 + j] = c_[j];
  }
  __syncthreads();
  // serial Thomas factorization: one leader lane per column (lanes 0, 32)
  if (segLane == 0) {
    float cpp = 0.f;
    for (int k = 0; k < NZv; ++k) {
      const float aa = sh_abc[wid][cw][0][k];
      const float bb = sh_abc[wid][cw][1][k];
      const float cc = sh_abc[wid][cw][2][k];
      const float den = bb - aa * cpp;
      const float pp  = 1.f / den;
      const float cpk = cc * pp;
      sh_cpp[wid][cw][0][k] = cpk;
      sh_cpp[wid][cw][1][k] = pp;
      cpp = cpk;
    }
  }
  __syncthreads();

  float p_[4], Ab_[4], A_[4];
#pragma unroll
  for (int j = 0; j < 4; ++j) {
    Ab_[j] = -sh_cpp[wid][cw][0][k0 + j];   // backward multiplier = -cp_k
    p_[j]  =  sh_cpp[wid][cw][1][k0 + j];   // 1/den
    A_[j]  = -a_[j] * p_[j];                // forward multiplier
  }
  float Ap[3];                              // forward carry weights
  Ap[0] = A_[0];
  Ap[1] = A_[1] * Ap[0];
  Ap[2] = A_[2] * Ap[1];
  // Ap[*] = 0 at segLane==0 (a[0]=0): no carry into level 0.
  float Absuf[4];                           // backward carry weights
  Absuf[3] = Ab_[3];
  Absuf[2] = Ab_[2] * Absuf[3];
  Absuf[1] = Ab_[1] * Absuf[2];
  Absuf[0] = Ab_[0] * Absuf[1];
  // Absuf[*] = 0 at segLane==31 (cp[127]=0): no carry into top level.

  // carry-path blend weights (0/1): full-exec fma blend, no divergence
  const float m16 = (segLane == 16) ? 1.f : 0.f;  // bcast15 valid here (fwd)
  const float m15 = (segLane == 15) ? 1.f : 0.f;  // swz16 valid here (bwd)

  // ---- forcing (fixed in time), prefolded with p_ ------------------------
  const float hz_top = hz[NZv - 1];
  const float g    = DTf * FCORf;
  const float cinv = 1.f / (1.f + g * g);
  float pfA[4], pci[4], pcg[4];
  float pfB3;
  if (!isM) {
#pragma unroll
    for (int j = 0; j < 4; ++j) {
      const int k = k0 + j;
      const float zk = zw[k], zk1 = zw[k + 1];
      const float fck  = RFLX_SFC * (0.58f * expf(zk  * (1.f / 0.35f)) + 0.42f * expf(zk  * (1.f / 23.f)));
      const float fck1 = RFLX_SFC * (0.58f * expf(zk1 * (1.f / 0.35f)) + 0.42f * expf(zk1 * (1.f / 23.f)));
      float div = (fck1 - fck) / hzv[j];
      if (k == NZv - 1) div += TFLX_SFC / hz_top;
      const float ec = 0.5f * (eps[col * (NZv + 1) + k] + eps[col * (NZv + 1) + k + 1]);
      pfA[j] = p_[j] * (DTf * (div + ec * (1.f / CPf)));   // t forcing
      pci[j] = p_[j];
      pcg[j] = 0.f;
    }
    pfB3 = (segLane == 31) ? p_[3] * (DTf * SFLX_SFC / hz_top) : 0.f;  // s
  } else {
#pragma unroll
    for (int j = 0; j < 4; ++j) {
      pfA[j] = 0.f;
      pci[j] = p_[j] * cinv;
      pcg[j] = pci[j] * g;
    }
    if (segLane == 31) pfA[3] = p_[3] * (DTf * USTR_SFC / hz_top);  // u stress
    pfB3 = 0.f;                        // v forcing zero (VSTR=BTM=0)
  }

  // ---- state load: field A = t|u, field B = s|v --------------------------
  const float* fpA = isM ? u_in : t_in;
  const float* fpB = isM ? v_in : s_in;
  float stA[4], stB[4];
  {
    const float4 av = *(const float4*)(fpA + (size_t)col * NZv + k0);
    stA[0] = av.x; stA[1] = av.y; stA[2] = av.z; stA[3] = av.w;
    const float4 bv = *(const float4*)(fpB + (size_t)col * NZv + k0);
    stB[0] = bv.x; stB[1] = bv.y; stB[2] = bv.z; stB[3] = bv.w;
  }
  const int fidxA = isM ? 0 : 2;            // u | t
  const int fidxB = isM ? 1 : 3;            // v | s
  float* outA = out + ((size_t)fidxA * NSNAP * Bv + col) * NZv + k0;
  float* outB = out + ((size_t)fidxB * NSNAP * Bv + col) * NZv + k0;

  // dual tridiag solve; carries via ROW-local ops only:
  //   X  = m16*bcast15(P3) + row_shr1(P3)   (same values wave_shr1 gave)
  //   Xb = m15*swz16(S0)   + row_shl1(S0)   (same values wave_shl1 gave)
  auto sweep2 = [&](const float* inA, const float* inB) {
    float PA[4], PB[4];
    PA[0] = inA[0]; PB[0] = inB[0];
#pragma unroll
    for (int j = 1; j < 4; ++j) {
      PA[j] = fmaf(A_[j], PA[j - 1], inA[j]);
      PB[j] = fmaf(A_[j], PB[j - 1], inB[j]);
    }
    const float shrA = dpp_zero<ROW_SHR1>(PA[3]);
    const float shrB = dpp_zero<ROW_SHR1>(PB[3]);
    const float bcA  = dpp_zero<ROW_BCAST15>(PA[3]);
    const float bcB  = dpp_zero<ROW_BCAST15>(PB[3]);
    const float XfA = fmaf(m16, bcA, shrA);
    const float XfB = fmaf(m16, bcB, shrB);
    float dA[4], dB[4];
    dA[3] = PA[3]; dB[3] = PB[3];
#pragma unroll
    for (int j = 0; j < 3; ++j) {
      dA[j] = fmaf(Ap[j], XfA, PA[j]);
      dB[j] = fmaf(Ap[j], XfB, PB[j]);
    }
    float SA[4], SB[4];
    SA[3] = dA[3]; SB[3] = dB[3];
#pragma unroll
    for (int j = 2; j >= 0; --j) {
      SA[j] = fmaf(Ab_[j], SA[j + 1], dA[j]);
      SB[j] = fmaf(Ab_[j], SB[j + 1], dB[j]);
    }
    const float shlA = dpp_zero<ROW_SHL1>(SA[0]);
    const float shlB = dpp_zero<ROW_SHL1>(SB[0]);
    const float swA  = swz16(SA[0]);
    const float swB  = swz16(SB[0]);
    const float XbA = fmaf(m15, swA, shlA);
    const float XbB = fmaf(m15, swB, shlB);
    stA[0] = SA[0]; stB[0] = SB[0];
#pragma unroll
    for (int j = 1; j < 4; ++j) {
      stA[j] = fmaf(Absuf[j], XbA, SA[j]);
      stB[j] = fmaf(Absuf[j], XbB, SB[j]);
    }
  };

  // ---- time loop ---------------------------------------------------------
  if (!isM) {
#pragma unroll 1
    for (int ch = 0; ch < NSNAP; ++ch) {
      *(float4*)(outA + (size_t)ch * Bv * NZv) = make_float4(stA[0], stA[1], stA[2], stA[3]);
      *(float4*)(outB + (size_t)ch * Bv * NZv) = make_float4(stB[0], stB[1], stB[2], stB[3]);
#pragma unroll 2
      for (int it = 0; it < NOUTv; ++it) {
        float inA[4], inB[4];
#pragma unroll
        for (int j = 0; j < 4; ++j) {
          inA[j] = fmaf(pci[j], stA[j], pfA[j]);                     // t
          inB[j] = fmaf(pci[j], stB[j], (j == 3) ? pfB3 : 0.f);      // s
        }
        sweep2(inA, inB);
      }
    }
  } else {
#pragma unroll 1
    for (int ch = 0; ch < NSNAP; ++ch) {
      *(float4*)(outA + (size_t)ch * Bv * NZv) = make_float4(stA[0], stA[1], stA[2], stA[3]);
      *(float4*)(outB + (size_t)ch * Bv * NZv) = make_float4(stB[0], stB[1], stB[2], stB[3]);
#pragma unroll 2
      for (int it = 0; it < NOUTv; ++it) {
        float inA[4], inB[4];
#pragma unroll
        for (int j = 0; j < 4; ++j) {
          // semi-implicit Coriolis, lane-local:
          inA[j] = fmaf(pci[j], stA[j], fmaf(pcg[j], stB[j], pfA[j])); // u
          inB[j] = fmaf(pci[j], stB[j], -(pcg[j] * stA[j]));           // v
        }
        sweep2(inA, inB);
      }
    }
  }
}

extern "C" void kernel_launch(void* const* d_in, const int* in_sizes, int n_in,
                              void* d_out, int out_size, void* d_ws, size_t ws_size,
                              hipStream_t stream) {
  const float* u   = (const float*)d_in[0];
  const float* v   = (const float*)d_in[1];
  const float* t   = (const float*)d_in[2];
  const float* s   = (const float*)d_in[3];
  const float* akv = (const float*)d_in[4];
  const float* akt = (const float*)d_in[5];
  const float* eps = (const float*)d_in[6];
  const float* hz  = (const float*)d_in[7];
  (void)in_sizes; (void)n_in; (void)d_ws; (void)ws_size; (void)out_size;
  // 512 blocks x 256 threads: block = 4 columns x {tracer, momentum} waves;
  // wave = 2 columns (32-lane segments, 4 levels/lane), fields in-lane.
  scm_kernel<<<dim3(Bv / 4), dim3(256), 0, stream>>>(
      u, v, t, s, akv, akt, eps, hz, (float*)d_out);
}